// Round 1
// baseline (1852.593 us; speedup 1.0000x reference)
//
#include <hip/hip_runtime.h>
#include <hip/hip_bf16.h>
#include <math.h>

// ---------------------------------------------------------------------------
// SAGPool-style GlobNet forward, MI355X.
// Phases: CSR build -> 3x (GEMM + edge-aggregate + relu) -> score GCN ->
//         radix-select top-K -> gated max/mean pool -> 3-layer MLP head.
// ---------------------------------------------------------------------------

#define WAVE 64

__device__ __forceinline__ unsigned f2ord(float f) {
    unsigned u = __float_as_uint(f);
    return u ^ ((u >> 31) ? 0xFFFFFFFFu : 0x80000000u);
}

// ---------------- CSR build ----------------

__global__ void k_meta_init(int* meta, int K) {
    meta[0] = K;   // kwant for pass 1
    // meta[1]=B, meta[2]=Kp, meta[3]=L, meta[4]=R, meta[5]=tie counter (memset 0)
}

__global__ void k_count(const int* __restrict__ dst, int* __restrict__ cnt, int E) {
    int e = blockIdx.x * 256 + threadIdx.x;
    if (e < E) atomicAdd(&cnt[dst[e]], 1);
}

__global__ void k_scan_a(const int* __restrict__ cnt, int* __restrict__ bsum, int n) {
    int t = threadIdx.x;
    int base = blockIdx.x * 1024 + t * 4;
    int s = 0;
#pragma unroll
    for (int c = 0; c < 4; ++c)
        if (base + c < n) s += cnt[base + c];
#pragma unroll
    for (int d = 32; d > 0; d >>= 1) s += __shfl_down(s, d);
    __shared__ int wsum[4];
    if ((t & 63) == 0) wsum[t >> 6] = s;
    __syncthreads();
    if (t == 0) bsum[blockIdx.x] = wsum[0] + wsum[1] + wsum[2] + wsum[3];
}

__global__ void k_scan_b(int* __restrict__ bsum, int nb, int* __restrict__ rowptr, int n) {
    if (threadIdx.x == 0) {
        int run = 0;
        for (int i = 0; i < nb; ++i) { int v = bsum[i]; bsum[i] = run; run += v; }
        rowptr[n] = run;  // == E
    }
}

__global__ void k_scan_c(const int* __restrict__ cnt, const int* __restrict__ bsum,
                         int* __restrict__ rowptr, float* __restrict__ dsq,
                         float* __restrict__ dinv, int n) {
    int t = threadIdx.x;
    int base = blockIdx.x * 1024 + t * 4;
    int v[4]; int s = 0;
#pragma unroll
    for (int c = 0; c < 4; ++c) { v[c] = (base + c < n) ? cnt[base + c] : 0; s += v[c]; }
    int lane = t & 63, wv = t >> 6;
    int x = s;
#pragma unroll
    for (int d = 1; d < 64; d <<= 1) { int y = __shfl_up(x, d); if (lane >= d) x += y; }
    int excl = x - s;
    __shared__ int wsum[4];
    if (lane == 63) wsum[wv] = x;
    __syncthreads();
    int off = bsum[blockIdx.x] + excl;
    for (int w = 0; w < wv; ++w) off += wsum[w];
#pragma unroll
    for (int c = 0; c < 4; ++c) {
        if (base + c < n) {
            rowptr[base + c] = off;
            off += v[c];
            float dg = (float)v[c] + 1.0f;
            dsq[base + c] = 1.0f / sqrtf(dg);
            dinv[base + c] = 1.0f / dg;
        }
    }
}

__global__ void k_fill(const int* __restrict__ src, const int* __restrict__ dst,
                       const int* __restrict__ rowptr, int* __restrict__ fill,
                       int* __restrict__ col, float* __restrict__ nrm,
                       const float* __restrict__ dsq, int E) {
    int e = blockIdx.x * 256 + threadIdx.x;
    if (e < E) {
        int s = src[e], d = dst[e];
        int pos = rowptr[d] + atomicAdd(&fill[d], 1);
        col[pos] = s;
        nrm[pos] = dsq[s] * dsq[d];
    }
}

// ---------------- GEMM: out[N,128] = A[N,KIN] @ W[KIN,128] ----------------

template <int KIN>
__global__ __launch_bounds__(256) void k_gemm(const float* __restrict__ A,
                                              const float* __restrict__ W,
                                              float* __restrict__ out, int nrows) {
    __shared__ float As[32][68];    // [k][row], padded (272B rows: 16B aligned)
    __shared__ float Bs[32][132];   // [k][col], padded (528B rows: 16B aligned)
    const int tid = threadIdx.x;
    const int row0 = blockIdx.x * 64;
    const int tcol = tid & 31;      // *4 -> col 0..127
    const int trow = tid >> 5;      // *8 -> row 0..63
    float acc[8][4] = {};

    for (int k0 = 0; k0 < KIN; k0 += 32) {
#pragma unroll
        for (int j = 0; j < 2; ++j) {   // A tile 64x32
            int g = tid + j * 256;      // 0..511
            int r = g >> 3, k4 = g & 7;
            float4 v = make_float4(0.f, 0.f, 0.f, 0.f);
            int gr = row0 + r;
            if (gr < nrows)
                v = *reinterpret_cast<const float4*>(&A[(size_t)gr * KIN + k0 + k4 * 4]);
            As[k4 * 4 + 0][r] = v.x; As[k4 * 4 + 1][r] = v.y;
            As[k4 * 4 + 2][r] = v.z; As[k4 * 4 + 3][r] = v.w;
        }
#pragma unroll
        for (int j = 0; j < 4; ++j) {   // W tile 32x128
            int g = tid + j * 256;      // 0..1023
            int r = g >> 5, c4 = g & 31;
            float4 v = *reinterpret_cast<const float4*>(&W[(size_t)(k0 + r) * 128 + c4 * 4]);
            *reinterpret_cast<float4*>(&Bs[r][c4 * 4]) = v;
        }
        __syncthreads();
#pragma unroll
        for (int kk = 0; kk < 32; ++kk) {
            float4 b = *reinterpret_cast<const float4*>(&Bs[kk][tcol * 4]);
            float4 a0 = *reinterpret_cast<const float4*>(&As[kk][trow * 8]);
            float4 a1 = *reinterpret_cast<const float4*>(&As[kk][trow * 8 + 4]);
            const float ar[8] = {a0.x, a0.y, a0.z, a0.w, a1.x, a1.y, a1.z, a1.w};
#pragma unroll
            for (int r = 0; r < 8; ++r) {
                acc[r][0] += ar[r] * b.x; acc[r][1] += ar[r] * b.y;
                acc[r][2] += ar[r] * b.z; acc[r][3] += ar[r] * b.w;
            }
        }
        __syncthreads();
    }
#pragma unroll
    for (int r = 0; r < 8; ++r) {
        int gr = row0 + trow * 8 + r;
        if (gr < nrows) {
            float4 v = make_float4(acc[r][0], acc[r][1], acc[r][2], acc[r][3]);
            *reinterpret_cast<float4*>(&out[(size_t)gr * 128 + tcol * 4]) = v;
        }
    }
}

// -------- aggregate: out[i] = relu(sum_e nrm*xw[col] + dinv[i]*xw[i] + b) --------

__global__ void k_aggregate(const float* __restrict__ xw, const int* __restrict__ rp,
                            const int* __restrict__ col, const float* __restrict__ nrm,
                            const float* __restrict__ dinv, const float* __restrict__ bias,
                            float* __restrict__ out, int n) {
    int i = blockIdx.x;
    int f = threadIdx.x;   // 128
    float acc = xw[(size_t)i * 128 + f] * dinv[i];
    int e0 = rp[i], e1 = rp[i + 1];
    for (int e = e0; e < e1; ++e) {
        int c = col[e];
        float w = nrm[e];
        acc += w * xw[(size_t)c * 128 + f];
    }
    out[(size_t)i * 128 + f] = fmaxf(acc + bias[f], 0.0f);
}

// ---------------- score GCN ----------------

__global__ void k_sw(const float* __restrict__ x1, const float* __restrict__ x2,
                     const float* __restrict__ x3, const float* __restrict__ Ws,
                     float* __restrict__ sw, int n) {
    int i = blockIdx.x;
    int l = threadIdx.x;  // 64
    size_t b = (size_t)i * 128;
    float v = x1[b + l] * Ws[l]       + x1[b + l + 64] * Ws[l + 64]
            + x2[b + l] * Ws[128 + l] + x2[b + l + 64] * Ws[192 + l]
            + x3[b + l] * Ws[256 + l] + x3[b + l + 64] * Ws[320 + l];
#pragma unroll
    for (int d = 32; d > 0; d >>= 1) v += __shfl_down(v, d);
    if (l == 0) sw[i] = v;
}

__global__ void k_score_agg(const float* __restrict__ sw, const int* __restrict__ rp,
                            const int* __restrict__ col, const float* __restrict__ nrm,
                            const float* __restrict__ dinv, const float* __restrict__ bs,
                            float* __restrict__ score, int n) {
    int i = blockIdx.x * 256 + threadIdx.x;
    if (i >= n) return;
    float s = sw[i] * dinv[i] + bs[0];
    int e0 = rp[i], e1 = rp[i + 1];
    for (int e = e0; e < e1; ++e) s += nrm[e] * sw[col[e]];
    score[i] = s;
}

// ---------------- top-K radix select ----------------

__global__ void k_hist1(const float* __restrict__ score, int* __restrict__ hist, int n) {
    int i = blockIdx.x * 256 + threadIdx.x;
    if (i < n) atomicAdd(&hist[f2ord(score[i]) >> 16], 1);
}

__global__ void k_hist2(const float* __restrict__ score, const int* __restrict__ meta,
                        int* __restrict__ hist, int n) {
    int i = blockIdx.x * 256 + threadIdx.x;
    if (i < n) {
        unsigned u = f2ord(score[i]);
        if ((int)(u >> 16) == meta[1]) atomicAdd(&hist[u & 0xFFFF], 1);
    }
}

// find bucket B s.t. cnt_gt(B) < kwant <= cnt_ge(B); outKp = kwant - cnt_gt(B)
__global__ void k_find_bucket(const int* __restrict__ hist, const int* __restrict__ kwant_p,
                              int* __restrict__ outB, int* __restrict__ outKp) {
    __shared__ int sh[256];
    __shared__ int seg_pick, seg_gt;
    int t = threadIdx.x;
    int kwant = *kwant_p;
    // phase 1: per-thread segment sums (thread t owns buckets [t*256, t*256+256))
    int s = 0;
    const int* hp = hist + t * 256;
    for (int j = 0; j < 256; ++j) s += hp[j];
    sh[t] = s;
    __syncthreads();
    for (int d = 1; d < 256; d <<= 1) {
        int add = (t + d < 256) ? sh[t + d] : 0;
        __syncthreads();
        sh[t] += add;
        __syncthreads();
    }
    int St = sh[t], Stn = (t < 255) ? sh[t + 1] : 0;
    if (St >= kwant && Stn < kwant) { seg_pick = t; seg_gt = Stn; }
    __syncthreads();
    // phase 2: scan the picked 256-bucket segment
    int base = seg_pick * 256;
    int v = hist[base + t];
    __syncthreads();
    sh[t] = v;
    __syncthreads();
    for (int d = 1; d < 256; d <<= 1) {
        int add = (t + d < 256) ? sh[t + d] : 0;
        __syncthreads();
        sh[t] += add;
        __syncthreads();
    }
    int st = sh[t], stn = (t < 255) ? sh[t + 1] : 0;
    int gt = seg_gt;
    if (gt + st >= kwant && gt + stn < kwant) {
        *outB = base + t;
        *outKp = kwant - (gt + stn);
    }
}

__global__ void k_select(const float* __restrict__ score, int* __restrict__ meta,
                         unsigned char* __restrict__ sel, float* __restrict__ gate, int n) {
    int i = blockIdx.x * 256 + threadIdx.x;
    if (i >= n) return;
    unsigned u = f2ord(score[i]);
    unsigned T = ((unsigned)meta[1] << 16) | (unsigned)meta[3];
    int R = meta[4];
    int s;
    if (u > T) s = 1;
    else if (u == T) { int r = atomicAdd(&meta[5], 1); s = (r < R) ? 1 : 0; }
    else s = 0;
    sel[i] = (unsigned char)s;
    gate[i] = tanhf(score[i]);
}

// ---------------- gated max/mean pool ----------------

__global__ void k_pool(const float* __restrict__ x1, const float* __restrict__ x2,
                       const float* __restrict__ x3, const unsigned char* __restrict__ sel,
                       const float* __restrict__ gate, float* __restrict__ pmax,
                       float* __restrict__ psum, int n) {
    int ch = blockIdx.x;          // node chunk
    int fg = blockIdx.y;          // feature group (6 x 64)
    int l = threadIdx.x;          // 64
    int f = fg * 64 + l;          // 0..383
    const float* buf = (f < 128) ? x1 : ((f < 256) ? x2 : x3);
    int ff = f & 127;
    int per = (n + gridDim.x - 1) / gridDim.x;
    int i0 = ch * per, i1 = min(n, i0 + per);
    float mx = -3.402823466e38f, sm = 0.f;
    for (int i = i0; i < i1; ++i) {
        if (sel[i]) {
            float v = buf[(size_t)i * 128 + ff] * gate[i];
            mx = fmaxf(mx, v);
            sm += v;
        }
    }
    pmax[ch * 384 + f] = mx;
    psum[ch * 384 + f] = sm;
}

__global__ void k_pool_final(const float* __restrict__ pmax, const float* __restrict__ psum,
                             float* __restrict__ hvec, int nch, int K) {
    int f = threadIdx.x;  // 384
    float mx = -3.402823466e38f, sm = 0.f;
    for (int c = 0; c < nch; ++c) {
        mx = fmaxf(mx, pmax[c * 384 + f]);
        sm += psum[c * 384 + f];
    }
    hvec[f] = mx;
    hvec[384 + f] = sm / (float)K;
}

// ---------------- MLP head + log_softmax ----------------

__global__ void k_head(const float* __restrict__ hvec,
                       const float* __restrict__ Wl1, const float* __restrict__ bl1,
                       const float* __restrict__ Wl2, const float* __restrict__ bl2,
                       const float* __restrict__ Wl3, const float* __restrict__ bl3,
                       float* __restrict__ out) {
    __shared__ float h[768];
    __shared__ float h1[128];
    __shared__ float h2[64];
    __shared__ float lg[10];
    int t = threadIdx.x;  // 128
    for (int j = t; j < 768; j += 128) h[j] = hvec[j];
    __syncthreads();
    {
        float a = bl1[t];
        for (int k = 0; k < 768; ++k) a += h[k] * Wl1[(size_t)k * 128 + t];
        h1[t] = fmaxf(a, 0.f);
    }
    __syncthreads();
    if (t < 64) {
        float a = bl2[t];
        for (int k = 0; k < 128; ++k) a += h1[k] * Wl2[(size_t)k * 64 + t];
        h2[t] = fmaxf(a, 0.f);
    }
    __syncthreads();
    if (t < 10) {
        float a = bl3[t];
        for (int k = 0; k < 64; ++k) a += h2[k] * Wl3[(size_t)k * 10 + t];
        lg[t] = a;
    }
    __syncthreads();
    if (t == 0) {
        float m = -3.402823466e38f;
        for (int c = 0; c < 10; ++c) m = fmaxf(m, lg[c]);
        float s = 0.f;
        for (int c = 0; c < 10; ++c) s += expf(lg[c] - m);
        float lse = logf(s);
        for (int c = 0; c < 10; ++c) lg[c] = lg[c] - m - lse;
    }
    __syncthreads();
    if (t < 10) out[t] = lg[t];
}

// ---------------------------------------------------------------------------

extern "C" void kernel_launch(void* const* d_in, const int* in_sizes, int n_in,
                              void* d_out, int out_size, void* d_ws, size_t ws_size,
                              hipStream_t stream) {
    const float* x   = (const float*)d_in[0];
    const int*   ei  = (const int*)d_in[1];
    const float* W1  = (const float*)d_in[3];
    const float* b1  = (const float*)d_in[4];
    const float* W2  = (const float*)d_in[5];
    const float* b2  = (const float*)d_in[6];
    const float* W3  = (const float*)d_in[7];
    const float* b3  = (const float*)d_in[8];
    const float* Ws  = (const float*)d_in[9];
    const float* bs  = (const float*)d_in[10];
    const float* Wl1 = (const float*)d_in[11];
    const float* bl1 = (const float*)d_in[12];
    const float* Wl2 = (const float*)d_in[13];
    const float* bl2 = (const float*)d_in[14];
    const float* Wl3 = (const float*)d_in[15];
    const float* bl3 = (const float*)d_in[16];
    float* out = (float*)d_out;

    const int N = in_sizes[2];       // 100000 (batch array length)
    const int E = in_sizes[1] / 2;   // 1600000
    const int K = (N + 1) / 2;       // ceil(0.5*N) = 50000
    const int* src = ei;
    const int* dst = ei + E;

    char* p = (char*)d_ws;
    auto alloc = [&](size_t bytes) -> void* {
        void* r = (void*)p;
        p += (bytes + 255) & ~(size_t)255;
        return r;
    };
    int*   cnt    = (int*)alloc((size_t)N * 4);
    int*   fill   = (int*)alloc((size_t)N * 4);
    int*   rowptr = (int*)alloc((size_t)(N + 1) * 4);
    int*   bsum   = (int*)alloc(256 * 4);
    float* dsq    = (float*)alloc((size_t)N * 4);
    float* dinv   = (float*)alloc((size_t)N * 4);
    int*   col    = (int*)alloc((size_t)E * 4);
    float* nrm    = (float*)alloc((size_t)E * 4);
    float* xw     = (float*)alloc((size_t)N * 128 * 4);
    float* x1     = (float*)alloc((size_t)N * 128 * 4);
    float* x2     = (float*)alloc((size_t)N * 128 * 4);
    float* x3     = (float*)alloc((size_t)N * 128 * 4);
    float* sw     = (float*)alloc((size_t)N * 4);
    float* score  = (float*)alloc((size_t)N * 4);
    float* gate   = (float*)alloc((size_t)N * 4);
    unsigned char* sel = (unsigned char*)alloc((size_t)N);
    int*   hist   = (int*)alloc(65536 * 4);
    int*   meta   = (int*)alloc(64 * 4);
    const int NCH = 64;
    float* pmax   = (float*)alloc((size_t)NCH * 384 * 4);
    float* psum   = (float*)alloc((size_t)NCH * 384 * 4);
    float* hvec   = (float*)alloc(768 * 4);

    const int NB_scan = (N + 1023) / 1024;
    const int GE = (E + 255) / 256;
    const int GN = (N + 255) / 256;
    const int GM = (N + 63) / 64;

    hipMemsetAsync(cnt, 0, (size_t)N * 4, stream);
    hipMemsetAsync(fill, 0, (size_t)N * 4, stream);
    hipMemsetAsync(meta, 0, 64 * 4, stream);
    k_meta_init<<<1, 1, 0, stream>>>(meta, K);

    k_count<<<GE, 256, 0, stream>>>(dst, cnt, E);
    k_scan_a<<<NB_scan, 256, 0, stream>>>(cnt, bsum, N);
    k_scan_b<<<1, 64, 0, stream>>>(bsum, NB_scan, rowptr, N);
    k_scan_c<<<NB_scan, 256, 0, stream>>>(cnt, bsum, rowptr, dsq, dinv, N);
    k_fill<<<GE, 256, 0, stream>>>(src, dst, rowptr, fill, col, nrm, dsq, E);

    k_gemm<512><<<GM, 256, 0, stream>>>(x, W1, xw, N);
    k_aggregate<<<N, 128, 0, stream>>>(xw, rowptr, col, nrm, dinv, b1, x1, N);
    k_gemm<128><<<GM, 256, 0, stream>>>(x1, W2, xw, N);
    k_aggregate<<<N, 128, 0, stream>>>(xw, rowptr, col, nrm, dinv, b2, x2, N);
    k_gemm<128><<<GM, 256, 0, stream>>>(x2, W3, xw, N);
    k_aggregate<<<N, 128, 0, stream>>>(xw, rowptr, col, nrm, dinv, b3, x3, N);

    k_sw<<<N, 64, 0, stream>>>(x1, x2, x3, Ws, sw, N);
    k_score_agg<<<GN, 256, 0, stream>>>(sw, rowptr, col, nrm, dinv, bs, score, N);

    hipMemsetAsync(hist, 0, 65536 * 4, stream);
    k_hist1<<<GN, 256, 0, stream>>>(score, hist, N);
    k_find_bucket<<<1, 256, 0, stream>>>(hist, meta + 0, meta + 1, meta + 2);
    hipMemsetAsync(hist, 0, 65536 * 4, stream);
    k_hist2<<<GN, 256, 0, stream>>>(score, meta, hist, N);
    k_find_bucket<<<1, 256, 0, stream>>>(hist, meta + 2, meta + 3, meta + 4);
    k_select<<<GN, 256, 0, stream>>>(score, meta, sel, gate, N);

    k_pool<<<dim3(NCH, 6), 64, 0, stream>>>(x1, x2, x3, sel, gate, pmax, psum, N);
    k_pool_final<<<1, 384, 0, stream>>>(pmax, psum, hvec, NCH, K);
    k_head<<<1, 128, 0, stream>>>(hvec, Wl1, bl1, Wl2, bl2, Wl3, bl3, out);
}

// Round 3
// 1457.060 us; speedup vs baseline: 1.2715x; 1.2715x over previous
//
#include <hip/hip_runtime.h>
#include <hip/hip_bf16.h>
#include <math.h>

// ---------------------------------------------------------------------------
// SAGPool-style GlobNet forward, MI355X.
// Phases: CSR build -> 3x (GEMM + edge-aggregate(+score-dot fused) + relu) ->
//         score aggregate -> radix-select top-K -> gated max/mean pool ->
//         3-layer MLP head.
// R1: k_pool parallelized (2048 chunks x 384 thr, was 384 waves total @ 3.9%
//     occupancy, 443us); k_sw folded into k_aggregate epilogue.
// R2: identical resubmit (R1 bench lost to GPU acquisition timeout).
// ---------------------------------------------------------------------------

#define WAVE 64

__device__ __forceinline__ unsigned f2ord(float f) {
    unsigned u = __float_as_uint(f);
    return u ^ ((u >> 31) ? 0xFFFFFFFFu : 0x80000000u);
}

// ---------------- CSR build ----------------

__global__ void k_meta_init(int* meta, int K) {
    meta[0] = K;   // kwant for pass 1
    // meta[1]=B, meta[2]=Kp, meta[3]=L, meta[4]=R, meta[5]=tie counter (memset 0)
}

__global__ void k_count(const int* __restrict__ dst, int* __restrict__ cnt, int E) {
    int e = blockIdx.x * 256 + threadIdx.x;
    if (e < E) atomicAdd(&cnt[dst[e]], 1);
}

__global__ void k_scan_a(const int* __restrict__ cnt, int* __restrict__ bsum, int n) {
    int t = threadIdx.x;
    int base = blockIdx.x * 1024 + t * 4;
    int s = 0;
#pragma unroll
    for (int c = 0; c < 4; ++c)
        if (base + c < n) s += cnt[base + c];
#pragma unroll
    for (int d = 32; d > 0; d >>= 1) s += __shfl_down(s, d);
    __shared__ int wsum[4];
    if ((t & 63) == 0) wsum[t >> 6] = s;
    __syncthreads();
    if (t == 0) bsum[blockIdx.x] = wsum[0] + wsum[1] + wsum[2] + wsum[3];
}

__global__ void k_scan_b(int* __restrict__ bsum, int nb, int* __restrict__ rowptr, int n) {
    if (threadIdx.x == 0) {
        int run = 0;
        for (int i = 0; i < nb; ++i) { int v = bsum[i]; bsum[i] = run; run += v; }
        rowptr[n] = run;  // == E
    }
}

__global__ void k_scan_c(const int* __restrict__ cnt, const int* __restrict__ bsum,
                         int* __restrict__ rowptr, float* __restrict__ dsq,
                         float* __restrict__ dinv, int n) {
    int t = threadIdx.x;
    int base = blockIdx.x * 1024 + t * 4;
    int v[4]; int s = 0;
#pragma unroll
    for (int c = 0; c < 4; ++c) { v[c] = (base + c < n) ? cnt[base + c] : 0; s += v[c]; }
    int lane = t & 63, wv = t >> 6;
    int x = s;
#pragma unroll
    for (int d = 1; d < 64; d <<= 1) { int y = __shfl_up(x, d); if (lane >= d) x += y; }
    int excl = x - s;
    __shared__ int wsum[4];
    if (lane == 63) wsum[wv] = x;
    __syncthreads();
    int off = bsum[blockIdx.x] + excl;
    for (int w = 0; w < wv; ++w) off += wsum[w];
#pragma unroll
    for (int c = 0; c < 4; ++c) {
        if (base + c < n) {
            rowptr[base + c] = off;
            off += v[c];
            float dg = (float)v[c] + 1.0f;
            dsq[base + c] = 1.0f / sqrtf(dg);
            dinv[base + c] = 1.0f / dg;
        }
    }
}

__global__ void k_fill(const int* __restrict__ src, const int* __restrict__ dst,
                       const int* __restrict__ rowptr, int* __restrict__ fill,
                       int* __restrict__ col, float* __restrict__ nrm,
                       const float* __restrict__ dsq, int E) {
    int e = blockIdx.x * 256 + threadIdx.x;
    if (e < E) {
        int s = src[e], d = dst[e];
        int pos = rowptr[d] + atomicAdd(&fill[d], 1);
        col[pos] = s;
        nrm[pos] = dsq[s] * dsq[d];
    }
}

// ---------------- GEMM: out[N,128] = A[N,KIN] @ W[KIN,128] ----------------

template <int KIN>
__global__ __launch_bounds__(256) void k_gemm(const float* __restrict__ A,
                                              const float* __restrict__ W,
                                              float* __restrict__ out, int nrows) {
    __shared__ float As[32][68];    // [k][row], padded
    __shared__ float Bs[32][132];   // [k][col], padded
    const int tid = threadIdx.x;
    const int row0 = blockIdx.x * 64;
    const int tcol = tid & 31;      // *4 -> col 0..127
    const int trow = tid >> 5;      // *8 -> row 0..63
    float acc[8][4] = {};

    for (int k0 = 0; k0 < KIN; k0 += 32) {
#pragma unroll
        for (int j = 0; j < 2; ++j) {   // A tile 64x32
            int g = tid + j * 256;      // 0..511
            int r = g >> 3, k4 = g & 7;
            float4 v = make_float4(0.f, 0.f, 0.f, 0.f);
            int gr = row0 + r;
            if (gr < nrows)
                v = *reinterpret_cast<const float4*>(&A[(size_t)gr * KIN + k0 + k4 * 4]);
            As[k4 * 4 + 0][r] = v.x; As[k4 * 4 + 1][r] = v.y;
            As[k4 * 4 + 2][r] = v.z; As[k4 * 4 + 3][r] = v.w;
        }
#pragma unroll
        for (int j = 0; j < 4; ++j) {   // W tile 32x128
            int g = tid + j * 256;      // 0..1023
            int r = g >> 5, c4 = g & 31;
            float4 v = *reinterpret_cast<const float4*>(&W[(size_t)(k0 + r) * 128 + c4 * 4]);
            *reinterpret_cast<float4*>(&Bs[r][c4 * 4]) = v;
        }
        __syncthreads();
#pragma unroll
        for (int kk = 0; kk < 32; ++kk) {
            float4 b = *reinterpret_cast<const float4*>(&Bs[kk][tcol * 4]);
            float4 a0 = *reinterpret_cast<const float4*>(&As[kk][trow * 8]);
            float4 a1 = *reinterpret_cast<const float4*>(&As[kk][trow * 8 + 4]);
            const float ar[8] = {a0.x, a0.y, a0.z, a0.w, a1.x, a1.y, a1.z, a1.w};
#pragma unroll
            for (int r = 0; r < 8; ++r) {
                acc[r][0] += ar[r] * b.x; acc[r][1] += ar[r] * b.y;
                acc[r][2] += ar[r] * b.z; acc[r][3] += ar[r] * b.w;
            }
        }
        __syncthreads();
    }
#pragma unroll
    for (int r = 0; r < 8; ++r) {
        int gr = row0 + trow * 8 + r;
        if (gr < nrows) {
            float4 v = make_float4(acc[r][0], acc[r][1], acc[r][2], acc[r][3]);
            *reinterpret_cast<float4*>(&out[(size_t)gr * 128 + tcol * 4]) = v;
        }
    }
}

// -------- aggregate: out[i] = relu(sum_e nrm*xw[col] + dinv[i]*xw[i] + b) --------
// Fused epilogue: sw[i] (+)= dot(out_row, Wseg)  -- the pre-aggregation score.

__global__ void k_aggregate(const float* __restrict__ xw, const int* __restrict__ rp,
                            const int* __restrict__ col, const float* __restrict__ nrm,
                            const float* __restrict__ dinv, const float* __restrict__ bias,
                            float* __restrict__ out, const float* __restrict__ Wseg,
                            float* __restrict__ sw, int accum, int n) {
    int i = blockIdx.x;
    int f = threadIdx.x;   // 128
    float acc = xw[(size_t)i * 128 + f] * dinv[i];
    int e0 = rp[i], e1 = rp[i + 1];
    for (int e = e0; e < e1; ++e) {
        int c = col[e];
        float w = nrm[e];
        acc += w * xw[(size_t)c * 128 + f];
    }
    float v = fmaxf(acc + bias[f], 0.0f);
    out[(size_t)i * 128 + f] = v;
    // score-dot epilogue (replaces the k_sw full re-read of x1,x2,x3)
    float r = v * Wseg[f];
#pragma unroll
    for (int d = 32; d > 0; d >>= 1) r += __shfl_down(r, d);
    __shared__ float wred[2];
    if ((f & 63) == 0) wred[f >> 6] = r;
    __syncthreads();
    if (f == 0) {
        float tot = wred[0] + wred[1];
        sw[i] = accum ? (sw[i] + tot) : tot;
    }
}

__global__ void k_score_agg(const float* __restrict__ sw, const int* __restrict__ rp,
                            const int* __restrict__ col, const float* __restrict__ nrm,
                            const float* __restrict__ dinv, const float* __restrict__ bs,
                            float* __restrict__ score, int n) {
    int i = blockIdx.x * 256 + threadIdx.x;
    if (i >= n) return;
    float s = sw[i] * dinv[i] + bs[0];
    int e0 = rp[i], e1 = rp[i + 1];
    for (int e = e0; e < e1; ++e) s += nrm[e] * sw[col[e]];
    score[i] = s;
}

// ---------------- top-K radix select ----------------

__global__ void k_hist1(const float* __restrict__ score, int* __restrict__ hist, int n) {
    int i = blockIdx.x * 256 + threadIdx.x;
    if (i < n) atomicAdd(&hist[f2ord(score[i]) >> 16], 1);
}

__global__ void k_hist2(const float* __restrict__ score, const int* __restrict__ meta,
                        int* __restrict__ hist, int n) {
    int i = blockIdx.x * 256 + threadIdx.x;
    if (i < n) {
        unsigned u = f2ord(score[i]);
        if ((int)(u >> 16) == meta[1]) atomicAdd(&hist[u & 0xFFFF], 1);
    }
}

// find bucket B s.t. cnt_gt(B) < kwant <= cnt_ge(B); outKp = kwant - cnt_gt(B)
__global__ void k_find_bucket(const int* __restrict__ hist, const int* __restrict__ kwant_p,
                              int* __restrict__ outB, int* __restrict__ outKp) {
    __shared__ int sh[256];
    __shared__ int seg_pick, seg_gt;
    int t = threadIdx.x;
    int kwant = *kwant_p;
    int s = 0;
    const int* hp = hist + t * 256;
    for (int j = 0; j < 256; ++j) s += hp[j];
    sh[t] = s;
    __syncthreads();
    for (int d = 1; d < 256; d <<= 1) {
        int add = (t + d < 256) ? sh[t + d] : 0;
        __syncthreads();
        sh[t] += add;
        __syncthreads();
    }
    int St = sh[t], Stn = (t < 255) ? sh[t + 1] : 0;
    if (St >= kwant && Stn < kwant) { seg_pick = t; seg_gt = Stn; }
    __syncthreads();
    int base = seg_pick * 256;
    int v = hist[base + t];
    __syncthreads();
    sh[t] = v;
    __syncthreads();
    for (int d = 1; d < 256; d <<= 1) {
        int add = (t + d < 256) ? sh[t + d] : 0;
        __syncthreads();
        sh[t] += add;
        __syncthreads();
    }
    int st = sh[t], stn = (t < 255) ? sh[t + 1] : 0;
    int gt = seg_gt;
    if (gt + st >= kwant && gt + stn < kwant) {
        *outB = base + t;
        *outKp = kwant - (gt + stn);
    }
}

__global__ void k_select(const float* __restrict__ score, int* __restrict__ meta,
                         unsigned char* __restrict__ sel, float* __restrict__ gate, int n) {
    int i = blockIdx.x * 256 + threadIdx.x;
    if (i >= n) return;
    unsigned u = f2ord(score[i]);
    unsigned T = ((unsigned)meta[1] << 16) | (unsigned)meta[3];
    int R = meta[4];
    int s;
    if (u > T) s = 1;
    else if (u == T) { int r = atomicAdd(&meta[5], 1); s = (r < R) ? 1 : 0; }
    else s = 0;
    sel[i] = (unsigned char)s;
    gate[i] = tanhf(score[i]);
}

// ---------------- gated max/mean pool ----------------
// R1: 2048 chunks x 384 threads (one thread per output feature). ~48 waves/CU.

#define NCH 2048

__global__ void k_pool(const float* __restrict__ x1, const float* __restrict__ x2,
                       const float* __restrict__ x3, const unsigned char* __restrict__ sel,
                       const float* __restrict__ gate, float* __restrict__ pmax,
                       float* __restrict__ psum, int n, int per) {
    int ch = blockIdx.x;          // node chunk
    int f = threadIdx.x;          // 0..383
    const float* buf = (f < 128) ? x1 : ((f < 256) ? x2 : x3);
    int ff = f & 127;
    int i0 = ch * per, i1 = min(n, i0 + per);
    float mx = -3.402823466e38f, sm = 0.f;
    for (int i = i0; i < i1; ++i) {
        if (sel[i]) {
            float v = buf[(size_t)i * 128 + ff] * gate[i];
            mx = fmaxf(mx, v);
            sm += v;
        }
    }
    pmax[(size_t)ch * 384 + f] = mx;
    psum[(size_t)ch * 384 + f] = sm;
}

__global__ void k_pool_final(const float* __restrict__ pmax, const float* __restrict__ psum,
                             float* __restrict__ hvec, int nch, int K) {
    int f = blockIdx.x;   // 0..383
    int t = threadIdx.x;  // 256
    float mx = -3.402823466e38f, sm = 0.f;
    for (int c = t; c < nch; c += 256) {
        mx = fmaxf(mx, pmax[(size_t)c * 384 + f]);
        sm += psum[(size_t)c * 384 + f];
    }
#pragma unroll
    for (int d = 32; d > 0; d >>= 1) {
        mx = fmaxf(mx, __shfl_down(mx, d));
        sm += __shfl_down(sm, d);
    }
    __shared__ float smx[4], ssm[4];
    if ((t & 63) == 0) { smx[t >> 6] = mx; ssm[t >> 6] = sm; }
    __syncthreads();
    if (t == 0) {
        mx = fmaxf(fmaxf(smx[0], smx[1]), fmaxf(smx[2], smx[3]));
        sm = ssm[0] + ssm[1] + ssm[2] + ssm[3];
        hvec[f] = mx;
        hvec[384 + f] = sm / (float)K;
    }
}

// ---------------- MLP head + log_softmax ----------------

__global__ void k_head(const float* __restrict__ hvec,
                       const float* __restrict__ Wl1, const float* __restrict__ bl1,
                       const float* __restrict__ Wl2, const float* __restrict__ bl2,
                       const float* __restrict__ Wl3, const float* __restrict__ bl3,
                       float* __restrict__ out) {
    __shared__ float h[768];
    __shared__ float h1[128];
    __shared__ float h2[64];
    __shared__ float lg[10];
    int t = threadIdx.x;  // 128
    for (int j = t; j < 768; j += 128) h[j] = hvec[j];
    __syncthreads();
    {
        float a = bl1[t];
        for (int k = 0; k < 768; ++k) a += h[k] * Wl1[(size_t)k * 128 + t];
        h1[t] = fmaxf(a, 0.f);
    }
    __syncthreads();
    if (t < 64) {
        float a = bl2[t];
        for (int k = 0; k < 128; ++k) a += h1[k] * Wl2[(size_t)k * 64 + t];
        h2[t] = fmaxf(a, 0.f);
    }
    __syncthreads();
    if (t < 10) {
        float a = bl3[t];
        for (int k = 0; k < 64; ++k) a += h2[k] * Wl3[(size_t)k * 10 + t];
        lg[t] = a;
    }
    __syncthreads();
    if (t == 0) {
        float m = -3.402823466e38f;
        for (int c = 0; c < 10; ++c) m = fmaxf(m, lg[c]);
        float s = 0.f;
        for (int c = 0; c < 10; ++c) s += expf(lg[c] - m);
        float lse = logf(s);
        for (int c = 0; c < 10; ++c) lg[c] = lg[c] - m - lse;
    }
    __syncthreads();
    if (t < 10) out[t] = lg[t];
}

// ---------------------------------------------------------------------------

extern "C" void kernel_launch(void* const* d_in, const int* in_sizes, int n_in,
                              void* d_out, int out_size, void* d_ws, size_t ws_size,
                              hipStream_t stream) {
    const float* x   = (const float*)d_in[0];
    const int*   ei  = (const int*)d_in[1];
    const float* W1  = (const float*)d_in[3];
    const float* b1  = (const float*)d_in[4];
    const float* W2  = (const float*)d_in[5];
    const float* b2  = (const float*)d_in[6];
    const float* W3  = (const float*)d_in[7];
    const float* b3  = (const float*)d_in[8];
    const float* Ws  = (const float*)d_in[9];
    const float* bs  = (const float*)d_in[10];
    const float* Wl1 = (const float*)d_in[11];
    const float* bl1 = (const float*)d_in[12];
    const float* Wl2 = (const float*)d_in[13];
    const float* bl2 = (const float*)d_in[14];
    const float* Wl3 = (const float*)d_in[15];
    const float* bl3 = (const float*)d_in[16];
    float* out = (float*)d_out;

    const int N = in_sizes[2];       // 100000
    const int E = in_sizes[1] / 2;   // 1600000
    const int K = (N + 1) / 2;       // 50000
    const int* src = ei;
    const int* dst = ei + E;

    char* p = (char*)d_ws;
    auto alloc = [&](size_t bytes) -> void* {
        void* r = (void*)p;
        p += (bytes + 255) & ~(size_t)255;
        return r;
    };
    int*   cnt    = (int*)alloc((size_t)N * 4);
    int*   fill   = (int*)alloc((size_t)N * 4);
    int*   rowptr = (int*)alloc((size_t)(N + 1) * 4);
    int*   bsum   = (int*)alloc(256 * 4);
    float* dsq    = (float*)alloc((size_t)N * 4);
    float* dinv   = (float*)alloc((size_t)N * 4);
    int*   col    = (int*)alloc((size_t)E * 4);
    float* nrm    = (float*)alloc((size_t)E * 4);
    float* xw     = (float*)alloc((size_t)N * 128 * 4);
    float* x1     = (float*)alloc((size_t)N * 128 * 4);
    float* x2     = (float*)alloc((size_t)N * 128 * 4);
    float* x3     = (float*)alloc((size_t)N * 128 * 4);
    float* sw     = (float*)alloc((size_t)N * 4);
    float* score  = (float*)alloc((size_t)N * 4);
    float* gate   = (float*)alloc((size_t)N * 4);
    unsigned char* sel = (unsigned char*)alloc((size_t)N);
    int*   hist   = (int*)alloc(65536 * 4);
    int*   meta   = (int*)alloc(64 * 4);
    float* pmax   = (float*)alloc((size_t)NCH * 384 * 4);
    float* psum   = (float*)alloc((size_t)NCH * 384 * 4);
    float* hvec   = (float*)alloc(768 * 4);

    const int NB_scan = (N + 1023) / 1024;
    const int GE = (E + 255) / 256;
    const int GN = (N + 255) / 256;
    const int GM = (N + 63) / 64;

    hipMemsetAsync(cnt, 0, (size_t)N * 4, stream);
    hipMemsetAsync(fill, 0, (size_t)N * 4, stream);
    hipMemsetAsync(meta, 0, 64 * 4, stream);
    k_meta_init<<<1, 1, 0, stream>>>(meta, K);

    k_count<<<GE, 256, 0, stream>>>(dst, cnt, E);
    k_scan_a<<<NB_scan, 256, 0, stream>>>(cnt, bsum, N);
    k_scan_b<<<1, 64, 0, stream>>>(bsum, NB_scan, rowptr, N);
    k_scan_c<<<NB_scan, 256, 0, stream>>>(cnt, bsum, rowptr, dsq, dinv, N);
    k_fill<<<GE, 256, 0, stream>>>(src, dst, rowptr, fill, col, nrm, dsq, E);

    k_gemm<512><<<GM, 256, 0, stream>>>(x, W1, xw, N);
    k_aggregate<<<N, 128, 0, stream>>>(xw, rowptr, col, nrm, dinv, b1, x1, Ws,       sw, 0, N);
    k_gemm<128><<<GM, 256, 0, stream>>>(x1, W2, xw, N);
    k_aggregate<<<N, 128, 0, stream>>>(xw, rowptr, col, nrm, dinv, b2, x2, Ws + 128, sw, 1, N);
    k_gemm<128><<<GM, 256, 0, stream>>>(x2, W3, xw, N);
    k_aggregate<<<N, 128, 0, stream>>>(xw, rowptr, col, nrm, dinv, b3, x3, Ws + 256, sw, 1, N);

    k_score_agg<<<GN, 256, 0, stream>>>(sw, rowptr, col, nrm, dinv, bs, score, N);

    hipMemsetAsync(hist, 0, 65536 * 4, stream);
    k_hist1<<<GN, 256, 0, stream>>>(score, hist, N);
    k_find_bucket<<<1, 256, 0, stream>>>(hist, meta + 0, meta + 1, meta + 2);
    hipMemsetAsync(hist, 0, 65536 * 4, stream);
    k_hist2<<<GN, 256, 0, stream>>>(score, meta, hist, N);
    k_find_bucket<<<1, 256, 0, stream>>>(hist, meta + 2, meta + 3, meta + 4);
    k_select<<<GN, 256, 0, stream>>>(score, meta, sel, gate, N);

    int per = (N + NCH - 1) / NCH;
    k_pool<<<NCH, 384, 0, stream>>>(x1, x2, x3, sel, gate, pmax, psum, N, per);
    k_pool_final<<<384, 256, 0, stream>>>(pmax, psum, hvec, NCH, K);
    k_head<<<1, 128, 0, stream>>>(hvec, Wl1, bl1, Wl2, bl2, Wl3, bl3, out);
}

// Round 4
// 1068.835 us; speedup vs baseline: 1.7333x; 1.3632x over previous
//
#include <hip/hip_runtime.h>
#include <hip/hip_bf16.h>
#include <math.h>

// ---------------------------------------------------------------------------
// SAGPool-style GlobNet forward, MI355X.
// R1: k_pool parallelized; k_sw folded into k_aggregate epilogue.
// R3: bf16 everywhere downstream of x (f32 accumulate):
//     - GEMMs -> MFMA 16x16x32 bf16 (was f32 VALU, 199us @ MfmaUtil 0)
//     - aggregate gathers read bf16 rows (256B/edge, was 512B)
//     - pool reads bf16
// ---------------------------------------------------------------------------

typedef unsigned int u32;
typedef unsigned short u16;
typedef short bf16x8 __attribute__((ext_vector_type(8)));
typedef float f32x4 __attribute__((ext_vector_type(4)));

__device__ __forceinline__ unsigned f2ord(float f) {
    unsigned u = __float_as_uint(f);
    return u ^ ((u >> 31) ? 0xFFFFFFFFu : 0x80000000u);
}
__device__ __forceinline__ u16 f2bf(float f) {
    __hip_bfloat16 h = __float2bfloat16(f);
    return *(u16*)&h;
}
__device__ __forceinline__ float blo(u32 u) { return __uint_as_float(u << 16); }
__device__ __forceinline__ float bhi(u32 u) { return __uint_as_float(u & 0xFFFF0000u); }
__device__ __forceinline__ u32 bpack(float x, float y) {
    return ((u32)f2bf(y) << 16) | (u32)f2bf(x);
}

// ---------------- CSR build ----------------

__global__ void k_meta_init(int* meta, int K) { meta[0] = K; }

__global__ void k_count(const int* __restrict__ dst, int* __restrict__ cnt, int E) {
    int e = blockIdx.x * 256 + threadIdx.x;
    if (e < E) atomicAdd(&cnt[dst[e]], 1);
}

__global__ void k_scan_a(const int* __restrict__ cnt, int* __restrict__ bsum, int n) {
    int t = threadIdx.x;
    int base = blockIdx.x * 1024 + t * 4;
    int s = 0;
#pragma unroll
    for (int c = 0; c < 4; ++c)
        if (base + c < n) s += cnt[base + c];
#pragma unroll
    for (int d = 32; d > 0; d >>= 1) s += __shfl_down(s, d);
    __shared__ int wsum[4];
    if ((t & 63) == 0) wsum[t >> 6] = s;
    __syncthreads();
    if (t == 0) bsum[blockIdx.x] = wsum[0] + wsum[1] + wsum[2] + wsum[3];
}

__global__ void k_scan_b(int* __restrict__ bsum, int nb, int* __restrict__ rowptr, int n) {
    if (threadIdx.x == 0) {
        int run = 0;
        for (int i = 0; i < nb; ++i) { int v = bsum[i]; bsum[i] = run; run += v; }
        rowptr[n] = run;
    }
}

__global__ void k_scan_c(const int* __restrict__ cnt, const int* __restrict__ bsum,
                         int* __restrict__ rowptr, float* __restrict__ dsq,
                         float* __restrict__ dinv, int n) {
    int t = threadIdx.x;
    int base = blockIdx.x * 1024 + t * 4;
    int v[4]; int s = 0;
#pragma unroll
    for (int c = 0; c < 4; ++c) { v[c] = (base + c < n) ? cnt[base + c] : 0; s += v[c]; }
    int lane = t & 63, wv = t >> 6;
    int x = s;
#pragma unroll
    for (int d = 1; d < 64; d <<= 1) { int y = __shfl_up(x, d); if (lane >= d) x += y; }
    int excl = x - s;
    __shared__ int wsum[4];
    if (lane == 63) wsum[wv] = x;
    __syncthreads();
    int off = bsum[blockIdx.x] + excl;
    for (int w = 0; w < wv; ++w) off += wsum[w];
#pragma unroll
    for (int c = 0; c < 4; ++c) {
        if (base + c < n) {
            rowptr[base + c] = off;
            off += v[c];
            float dg = (float)v[c] + 1.0f;
            dsq[base + c] = 1.0f / sqrtf(dg);
            dinv[base + c] = 1.0f / dg;
        }
    }
}

__global__ void k_fill(const int* __restrict__ src, const int* __restrict__ dst,
                       const int* __restrict__ rowptr, int* __restrict__ fill,
                       int* __restrict__ col, float* __restrict__ nrm,
                       const float* __restrict__ dsq, int E) {
    int e = blockIdx.x * 256 + threadIdx.x;
    if (e < E) {
        int s = src[e], d = dst[e];
        int pos = rowptr[d] + atomicAdd(&fill[d], 1);
        col[pos] = s;
        nrm[pos] = dsq[s] * dsq[d];
    }
}

// ---------------- W transpose + bf16 prep: Wt[c][k] = bf16(W[k][c]) ----------------

__global__ void k_wprep(const float* __restrict__ W, u16* __restrict__ Wt, int KIN) {
    int idx = blockIdx.x * 256 + threadIdx.x;
    if (idx < 128 * KIN) {
        int c = idx / KIN, k = idx - c * KIN;
        Wt[idx] = f2bf(W[(size_t)k * 128 + c]);
    }
}

// ---------------- MFMA GEMM: outb[N,128]bf16 = A[N,KIN] @ W[KIN,128] ----------------
// A either f32 (convert at load) or bf16. Wt is [128][KIN] bf16 (i.e. W^T).
// Block: 256 thr (4 waves), tile 64 rows x 128 cols, BK=64.
// Frags (verified layout, learn_hip m89/m91/m97): A row=lane&15, k=(lane>>4)*8
// contiguous; B col=lane&15, same k; D col=lane&15, row=(lane>>4)*4+reg.

#define APAD 72
#define BPAD 72

template <int KIN, bool ABF16>
__global__ __launch_bounds__(256) void k_gemm_mfma(const void* __restrict__ Ain,
                                                   const u16* __restrict__ Wt,
                                                   u16* __restrict__ outb, int nrows) {
    __shared__ u16 lds[64 * APAD + 128 * BPAD];   // 27.6 KB
    u16* As = lds;                 // [64][APAD]
    u16* Bs = lds + 64 * APAD;     // [128][BPAD]
    const int tid = threadIdx.x;
    const int lane = tid & 63;
    const int wv = tid >> 6;       // 0..3
    const int row0 = blockIdx.x * 64;

    f32x4 acc[8] = {};

    const int ar = tid >> 2;            // 0..63 (A-tile row)
    const int akq = (tid & 3) * 16;     // 0/16/32/48 (A-tile k chunk)
    const int bc = tid >> 1;            // 0..127 (B-tile col)
    const int bko = (tid & 1) * 32;     // 0/32

    for (int k0 = 0; k0 < KIN; k0 += 64) {
        // ---- stage A tile 64x64 -> bf16 LDS ----
        {
            int gr = row0 + ar;
            u16* dp = &As[ar * APAD + akq];
            if (!ABF16) {
                const float* A = (const float*)Ain;
                float va[16];
                if (gr < nrows) {
                    const float* ap = &A[(size_t)gr * KIN + k0 + akq];
                    *(float4*)&va[0]  = ((const float4*)ap)[0];
                    *(float4*)&va[4]  = ((const float4*)ap)[1];
                    *(float4*)&va[8]  = ((const float4*)ap)[2];
                    *(float4*)&va[12] = ((const float4*)ap)[3];
                } else {
#pragma unroll
                    for (int j = 0; j < 16; ++j) va[j] = 0.f;
                }
                u16 tmp[16];
#pragma unroll
                for (int j = 0; j < 16; ++j) tmp[j] = f2bf(va[j]);
                *(uint4*)&dp[0] = *(uint4*)&tmp[0];
                *(uint4*)&dp[8] = *(uint4*)&tmp[8];
            } else {
                const u16* A = (const u16*)Ain;
                uint4 v0, v1;
                if (gr < nrows) {
                    const uint4* ap = (const uint4*)&A[(size_t)gr * KIN + k0 + akq];
                    v0 = ap[0]; v1 = ap[1];
                } else {
                    v0 = make_uint4(0, 0, 0, 0); v1 = v0;
                }
                *(uint4*)&dp[0] = v0;
                *(uint4*)&dp[8] = v1;
            }
        }
        // ---- stage B tile 128x64 (W^T) -> LDS ----
        {
            const uint4* wp = (const uint4*)&Wt[(size_t)bc * KIN + k0 + bko];
            u16* dp = &Bs[bc * BPAD + bko];
            ((uint4*)dp)[0] = wp[0];
            ((uint4*)dp)[1] = wp[1];
            ((uint4*)dp)[2] = wp[2];
            ((uint4*)dp)[3] = wp[3];
        }
        __syncthreads();
#pragma unroll
        for (int kc = 0; kc < 2; ++kc) {
            bf16x8 a = *(const bf16x8*)&As[(wv * 16 + (lane & 15)) * APAD + kc * 32 + (lane >> 4) * 8];
#pragma unroll
            for (int cf = 0; cf < 8; ++cf) {
                bf16x8 b = *(const bf16x8*)&Bs[(cf * 16 + (lane & 15)) * BPAD + kc * 32 + (lane >> 4) * 8];
                acc[cf] = __builtin_amdgcn_mfma_f32_16x16x32_bf16(a, b, acc[cf], 0, 0, 0);
            }
        }
        __syncthreads();
    }

    // ---- epilogue: stage C in LDS (bf16), then coalesced 64B stores ----
    u16* Cs = lds;   // [64][128], 16 KB (safe: all mfma LDS reads drained)
#pragma unroll
    for (int cf = 0; cf < 8; ++cf) {
#pragma unroll
        for (int j = 0; j < 4; ++j) {
            int row = wv * 16 + (lane >> 4) * 4 + j;
            int colc = cf * 16 + (lane & 15);
            Cs[row * 128 + colc] = f2bf(acc[cf][j]);
        }
    }
    __syncthreads();
    {
        int r = tid >> 2;
        int co = (tid & 3) * 32;
        int gr = row0 + r;
        if (gr < nrows) {
            uint4* dst = (uint4*)&outb[(size_t)gr * 128 + co];
            uint4* srcp = (uint4*)&Cs[r * 128 + co];
            dst[0] = srcp[0]; dst[1] = srcp[1]; dst[2] = srcp[2]; dst[3] = srcp[3];
        }
    }
}

// -------- aggregate (bf16): out[i] = relu(sum_e nrm*xw[col] + dinv[i]*xw[i] + b) -----
// 1 wave per node; features packed bf16x2 per lane. Score-dot epilogue fused.

__global__ void k_aggregate_bf(const u32* __restrict__ xw, const int* __restrict__ rp,
                               const int* __restrict__ col, const float* __restrict__ nrm,
                               const float* __restrict__ dinv, const float* __restrict__ bias,
                               u32* __restrict__ outb, const float* __restrict__ Wseg,
                               float* __restrict__ sw, int accum, int n) {
    int i = blockIdx.x;
    int l = threadIdx.x;   // 0..63
    u32 u = xw[(size_t)i * 64 + l];
    float di = dinv[i];
    float ax = blo(u) * di, ay = bhi(u) * di;
    int e0 = rp[i], e1 = rp[i + 1];
    for (int e = e0; e < e1; ++e) {
        int c = col[e];
        float w = nrm[e];
        u32 v = xw[(size_t)c * 64 + l];
        ax += w * blo(v);
        ay += w * bhi(v);
    }
    ax = fmaxf(ax + bias[2 * l], 0.f);
    ay = fmaxf(ay + bias[2 * l + 1], 0.f);
    outb[(size_t)i * 64 + l] = bpack(ax, ay);
    // fused score-dot
    float r = ax * Wseg[2 * l] + ay * Wseg[2 * l + 1];
#pragma unroll
    for (int d = 32; d > 0; d >>= 1) r += __shfl_down(r, d);
    if (l == 0) sw[i] = accum ? (sw[i] + r) : r;
}

__global__ void k_score_agg(const float* __restrict__ sw, const int* __restrict__ rp,
                            const int* __restrict__ col, const float* __restrict__ nrm,
                            const float* __restrict__ dinv, const float* __restrict__ bs,
                            float* __restrict__ score, int n) {
    int i = blockIdx.x * 256 + threadIdx.x;
    if (i >= n) return;
    float s = sw[i] * dinv[i] + bs[0];
    int e0 = rp[i], e1 = rp[i + 1];
    for (int e = e0; e < e1; ++e) s += nrm[e] * sw[col[e]];
    score[i] = s;
}

// ---------------- top-K radix select ----------------

__global__ void k_hist1(const float* __restrict__ score, int* __restrict__ hist, int n) {
    int i = blockIdx.x * 256 + threadIdx.x;
    if (i < n) atomicAdd(&hist[f2ord(score[i]) >> 16], 1);
}

__global__ void k_hist2(const float* __restrict__ score, const int* __restrict__ meta,
                        int* __restrict__ hist, int n) {
    int i = blockIdx.x * 256 + threadIdx.x;
    if (i < n) {
        unsigned u = f2ord(score[i]);
        if ((int)(u >> 16) == meta[1]) atomicAdd(&hist[u & 0xFFFF], 1);
    }
}

__global__ void k_find_bucket(const int* __restrict__ hist, const int* __restrict__ kwant_p,
                              int* __restrict__ outB, int* __restrict__ outKp) {
    __shared__ int sh[256];
    __shared__ int seg_pick, seg_gt;
    int t = threadIdx.x;
    int kwant = *kwant_p;
    int s = 0;
    const int* hp = hist + t * 256;
    for (int j = 0; j < 256; ++j) s += hp[j];
    sh[t] = s;
    __syncthreads();
    for (int d = 1; d < 256; d <<= 1) {
        int add = (t + d < 256) ? sh[t + d] : 0;
        __syncthreads();
        sh[t] += add;
        __syncthreads();
    }
    int St = sh[t], Stn = (t < 255) ? sh[t + 1] : 0;
    if (St >= kwant && Stn < kwant) { seg_pick = t; seg_gt = Stn; }
    __syncthreads();
    int base = seg_pick * 256;
    int v = hist[base + t];
    __syncthreads();
    sh[t] = v;
    __syncthreads();
    for (int d = 1; d < 256; d <<= 1) {
        int add = (t + d < 256) ? sh[t + d] : 0;
        __syncthreads();
        sh[t] += add;
        __syncthreads();
    }
    int st = sh[t], stn = (t < 255) ? sh[t + 1] : 0;
    int gt = seg_gt;
    if (gt + st >= kwant && gt + stn < kwant) {
        *outB = base + t;
        *outKp = kwant - (gt + stn);
    }
}

__global__ void k_select(const float* __restrict__ score, int* __restrict__ meta,
                         unsigned char* __restrict__ sel, float* __restrict__ gate, int n) {
    int i = blockIdx.x * 256 + threadIdx.x;
    if (i >= n) return;
    unsigned u = f2ord(score[i]);
    unsigned T = ((unsigned)meta[1] << 16) | (unsigned)meta[3];
    int R = meta[4];
    int s;
    if (u > T) s = 1;
    else if (u == T) { int r = atomicAdd(&meta[5], 1); s = (r < R) ? 1 : 0; }
    else s = 0;
    sel[i] = (unsigned char)s;
    gate[i] = tanhf(score[i]);
}

// ---------------- gated max/mean pool (bf16 inputs) ----------------
// 2048 chunks x 192 threads; thread t owns features {2*(t&63), +1} of buf t>>6.

#define NCH 2048

__global__ void k_pool(const u32* __restrict__ x1, const u32* __restrict__ x2,
                       const u32* __restrict__ x3, const unsigned char* __restrict__ sel,
                       const float* __restrict__ gate, float* __restrict__ pmax,
                       float* __restrict__ psum, int n, int per) {
    int ch = blockIdx.x;
    int t = threadIdx.x;                 // 0..191
    const u32* buf = (t < 64) ? x1 : ((t < 128) ? x2 : x3);
    int ff = t & 63;
    int f0 = (t >> 6) * 128 + 2 * ff;    // feature index of .lo
    int i0 = ch * per, i1 = min(n, i0 + per);
    float mx0 = -3.402823466e38f, mx1 = -3.402823466e38f, sm0 = 0.f, sm1 = 0.f;
    for (int i = i0; i < i1; ++i) {
        if (sel[i]) {
            float g = gate[i];
            u32 u = buf[(size_t)i * 64 + ff];
            float v0 = blo(u) * g, v1 = bhi(u) * g;
            mx0 = fmaxf(mx0, v0); sm0 += v0;
            mx1 = fmaxf(mx1, v1); sm1 += v1;
        }
    }
    pmax[(size_t)ch * 384 + f0] = mx0;
    pmax[(size_t)ch * 384 + f0 + 1] = mx1;
    psum[(size_t)ch * 384 + f0] = sm0;
    psum[(size_t)ch * 384 + f0 + 1] = sm1;
}

__global__ void k_pool_final(const float* __restrict__ pmax, const float* __restrict__ psum,
                             float* __restrict__ hvec, int nch, int K) {
    int f = blockIdx.x;   // 0..383
    int t = threadIdx.x;  // 256
    float mx = -3.402823466e38f, sm = 0.f;
    for (int c = t; c < nch; c += 256) {
        mx = fmaxf(mx, pmax[(size_t)c * 384 + f]);
        sm += psum[(size_t)c * 384 + f];
    }
#pragma unroll
    for (int d = 32; d > 0; d >>= 1) {
        mx = fmaxf(mx, __shfl_down(mx, d));
        sm += __shfl_down(sm, d);
    }
    __shared__ float smx[4], ssm[4];
    if ((t & 63) == 0) { smx[t >> 6] = mx; ssm[t >> 6] = sm; }
    __syncthreads();
    if (t == 0) {
        mx = fmaxf(fmaxf(smx[0], smx[1]), fmaxf(smx[2], smx[3]));
        sm = ssm[0] + ssm[1] + ssm[2] + ssm[3];
        hvec[f] = mx;
        hvec[384 + f] = sm / (float)K;
    }
}

// ---------------- MLP head + log_softmax ----------------

__global__ void k_head(const float* __restrict__ hvec,
                       const float* __restrict__ Wl1, const float* __restrict__ bl1,
                       const float* __restrict__ Wl2, const float* __restrict__ bl2,
                       const float* __restrict__ Wl3, const float* __restrict__ bl3,
                       float* __restrict__ out) {
    __shared__ float h[768];
    __shared__ float h1[128];
    __shared__ float h2[64];
    __shared__ float lg[10];
    int t = threadIdx.x;  // 128
    for (int j = t; j < 768; j += 128) h[j] = hvec[j];
    __syncthreads();
    {
        float a = bl1[t];
        for (int k = 0; k < 768; ++k) a += h[k] * Wl1[(size_t)k * 128 + t];
        h1[t] = fmaxf(a, 0.f);
    }
    __syncthreads();
    if (t < 64) {
        float a = bl2[t];
        for (int k = 0; k < 128; ++k) a += h1[k] * Wl2[(size_t)k * 64 + t];
        h2[t] = fmaxf(a, 0.f);
    }
    __syncthreads();
    if (t < 10) {
        float a = bl3[t];
        for (int k = 0; k < 64; ++k) a += h2[k] * Wl3[(size_t)k * 10 + t];
        lg[t] = a;
    }
    __syncthreads();
    if (t == 0) {
        float m = -3.402823466e38f;
        for (int c = 0; c < 10; ++c) m = fmaxf(m, lg[c]);
        float s = 0.f;
        for (int c = 0; c < 10; ++c) s += expf(lg[c] - m);
        float lse = logf(s);
        for (int c = 0; c < 10; ++c) lg[c] = lg[c] - m - lse;
    }
    __syncthreads();
    if (t < 10) out[t] = lg[t];
}

// ---------------------------------------------------------------------------

extern "C" void kernel_launch(void* const* d_in, const int* in_sizes, int n_in,
                              void* d_out, int out_size, void* d_ws, size_t ws_size,
                              hipStream_t stream) {
    const float* x   = (const float*)d_in[0];
    const int*   ei  = (const int*)d_in[1];
    const float* W1  = (const float*)d_in[3];
    const float* b1  = (const float*)d_in[4];
    const float* W2  = (const float*)d_in[5];
    const float* b2  = (const float*)d_in[6];
    const float* W3  = (const float*)d_in[7];
    const float* b3  = (const float*)d_in[8];
    const float* Ws  = (const float*)d_in[9];
    const float* bs  = (const float*)d_in[10];
    const float* Wl1 = (const float*)d_in[11];
    const float* bl1 = (const float*)d_in[12];
    const float* Wl2 = (const float*)d_in[13];
    const float* bl2 = (const float*)d_in[14];
    const float* Wl3 = (const float*)d_in[15];
    const float* bl3 = (const float*)d_in[16];
    float* out = (float*)d_out;

    const int N = in_sizes[2];       // 100000
    const int E = in_sizes[1] / 2;   // 1600000
    const int K = (N + 1) / 2;       // 50000
    const int* src = ei;
    const int* dst = ei + E;

    char* p = (char*)d_ws;
    auto alloc = [&](size_t bytes) -> void* {
        void* r = (void*)p;
        p += (bytes + 255) & ~(size_t)255;
        return r;
    };
    int*   cnt    = (int*)alloc((size_t)N * 4);
    int*   fill   = (int*)alloc((size_t)N * 4);
    int*   rowptr = (int*)alloc((size_t)(N + 1) * 4);
    int*   bsum   = (int*)alloc(256 * 4);
    float* dsq    = (float*)alloc((size_t)N * 4);
    float* dinv   = (float*)alloc((size_t)N * 4);
    int*   col    = (int*)alloc((size_t)E * 4);
    float* nrm    = (float*)alloc((size_t)E * 4);
    u32*   xw     = (u32*)alloc((size_t)N * 64 * 4);   // bf16 [N][128]
    u32*   x1     = (u32*)alloc((size_t)N * 64 * 4);
    u32*   x2     = (u32*)alloc((size_t)N * 64 * 4);
    u32*   x3     = (u32*)alloc((size_t)N * 64 * 4);
    u16*   Wt1    = (u16*)alloc((size_t)512 * 128 * 2);
    u16*   Wt2    = (u16*)alloc((size_t)128 * 128 * 2);
    u16*   Wt3    = (u16*)alloc((size_t)128 * 128 * 2);
    float* sw     = (float*)alloc((size_t)N * 4);
    float* score  = (float*)alloc((size_t)N * 4);
    float* gate   = (float*)alloc((size_t)N * 4);
    unsigned char* sel = (unsigned char*)alloc((size_t)N);
    int*   hist   = (int*)alloc(65536 * 4);
    int*   meta   = (int*)alloc(64 * 4);
    float* pmax   = (float*)alloc((size_t)NCH * 384 * 4);
    float* psum   = (float*)alloc((size_t)NCH * 384 * 4);
    float* hvec   = (float*)alloc(768 * 4);

    const int NB_scan = (N + 1023) / 1024;
    const int GE = (E + 255) / 256;
    const int GN = (N + 255) / 256;
    const int GM = (N + 63) / 64;   // 64-row GEMM tiles

    hipMemsetAsync(cnt, 0, (size_t)N * 4, stream);
    hipMemsetAsync(fill, 0, (size_t)N * 4, stream);
    hipMemsetAsync(meta, 0, 64 * 4, stream);
    k_meta_init<<<1, 1, 0, stream>>>(meta, K);

    k_count<<<GE, 256, 0, stream>>>(dst, cnt, E);
    k_scan_a<<<NB_scan, 256, 0, stream>>>(cnt, bsum, N);
    k_scan_b<<<1, 64, 0, stream>>>(bsum, NB_scan, rowptr, N);
    k_scan_c<<<NB_scan, 256, 0, stream>>>(cnt, bsum, rowptr, dsq, dinv, N);
    k_fill<<<GE, 256, 0, stream>>>(src, dst, rowptr, fill, col, nrm, dsq, E);

    k_wprep<<<(512 * 128 + 255) / 256, 256, 0, stream>>>(W1, Wt1, 512);
    k_wprep<<<(128 * 128 + 255) / 256, 256, 0, stream>>>(W2, Wt2, 128);
    k_wprep<<<(128 * 128 + 255) / 256, 256, 0, stream>>>(W3, Wt3, 128);

    k_gemm_mfma<512, false><<<GM, 256, 0, stream>>>(x, Wt1, (u16*)xw, N);
    k_aggregate_bf<<<N, 64, 0, stream>>>(xw, rowptr, col, nrm, dinv, b1, x1, Ws,       sw, 0, N);
    k_gemm_mfma<128, true><<<GM, 256, 0, stream>>>(x1, Wt2, (u16*)xw, N);
    k_aggregate_bf<<<N, 64, 0, stream>>>(xw, rowptr, col, nrm, dinv, b2, x2, Ws + 128, sw, 1, N);
    k_gemm_mfma<128, true><<<GM, 256, 0, stream>>>(x2, Wt3, (u16*)xw, N);
    k_aggregate_bf<<<N, 64, 0, stream>>>(xw, rowptr, col, nrm, dinv, b3, x3, Ws + 256, sw, 1, N);

    k_score_agg<<<GN, 256, 0, stream>>>(sw, rowptr, col, nrm, dinv, bs, score, N);

    hipMemsetAsync(hist, 0, 65536 * 4, stream);
    k_hist1<<<GN, 256, 0, stream>>>(score, hist, N);
    k_find_bucket<<<1, 256, 0, stream>>>(hist, meta + 0, meta + 1, meta + 2);
    hipMemsetAsync(hist, 0, 65536 * 4, stream);
    k_hist2<<<GN, 256, 0, stream>>>(score, meta, hist, N);
    k_find_bucket<<<1, 256, 0, stream>>>(hist, meta + 2, meta + 3, meta + 4);
    k_select<<<GN, 256, 0, stream>>>(score, meta, sel, gate, N);

    int per = (N + NCH - 1) / NCH;
    k_pool<<<NCH, 192, 0, stream>>>(x1, x2, x3, sel, gate, pmax, psum, N, per);
    k_pool_final<<<384, 256, 0, stream>>>(pmax, psum, hvec, NCH, K);
    k_head<<<1, 128, 0, stream>>>(hvec, Wl1, bl1, Wl2, bl2, Wl3, bl3, out);
}